// Round 21
// baseline (57.693 us; speedup 1.0000x reference)
//
#include <hip/hip_runtime.h>
#include <math.h>

#define NN 4096
#define DD 128
#define ALPHA_C 16.0f
#define KSEL 32         // threshold = (K+1)-th smallest, 0-based index K
#define P2F -0.19f      // pivot: rank-32 of N(0,1/128) sims is ~-0.213, below P2
#define NCAP 48         // normal slots per (row, col-supertile)
#define MCAP 6          // mirrored slots per (row, col-supertile, sub-job)
#define GSTR 48         // group stride in winbuf
#define RSLOT 768       // 16 groups * GSTR slots per row

typedef __attribute__((ext_vector_type(8))) short bf16x8;
typedef __attribute__((ext_vector_type(4))) float f32x4;

// ---- float <-> order-preserving u32 key ----
__device__ __forceinline__ unsigned f2k(float f) {
  unsigned b = __float_as_uint(f);
  return (b & 0x80000000u) ? ~b : (b | 0x80000000u);
}
__device__ __forceinline__ float k2f(unsigned k) {
  unsigned b = (k & 0x80000000u) ? (k & 0x7FFFFFFFu) : ~k;
  return __uint_as_float(b);
}

// ---- wave (64-lane) butterfly reductions ----
__device__ __forceinline__ double wsum_d(double v) {
  #pragma unroll
  for (int m = 32; m; m >>= 1) v += __shfl_xor(v, m, 64);
  return v;
}
__device__ __forceinline__ int wsum_i(int v) {
  #pragma unroll
  for (int m = 32; m; m >>= 1) v += __shfl_xor(v, m, 64);
  return v;
}
__device__ __forceinline__ float wsum_f(float v) {
  #pragma unroll
  for (int m = 32; m; m >>= 1) v += __shfl_xor(v, m, 64);
  return v;
}
__device__ __forceinline__ float wmin_f(float v) {
  #pragma unroll
  for (int m = 32; m; m >>= 1) v = fminf(v, __shfl_xor(v, m, 64));
  return v;
}

// ---- kernel 1: split x -> bf16 hi/lo fragment-major; f64 self-dots ----
__global__ __launch_bounds__(256) void nca_prep(
    const float* __restrict__ x, short* __restrict__ xhi, short* __restrict__ xlo,
    double* __restrict__ selfdot, float* __restrict__ diagneg,
    int* __restrict__ flag) {
  __shared__ double sd[16][16];

  const int tid = threadIdx.x;
  const int f  = blockIdx.x * 256 + tid;   // 0 .. N*D/8-1
  if (f == 0) flag[0] = 0;
  if (blockIdx.x == 0 && tid < 136) diagneg[tid] = 0.f;
  const int l  = f & 63;
  const int kb = (f >> 6) & 3;
  const int rg = f >> 8;                   // == blockIdx.x
  const int rloc = l & 15;
  const int row = (rg << 4) + rloc;
  const int k0  = (kb << 5) + ((l >> 4) << 3);
  const float* src = x + (size_t)row * DD + k0;
  float4 v0 = *reinterpret_cast<const float4*>(src);
  float4 v1 = *reinterpret_cast<const float4*>(src + 4);
  float vv[8] = {v0.x, v0.y, v0.z, v0.w, v1.x, v1.y, v1.z, v1.w};
  bf16x8 h, lo;
  double sdp = 0.0;
  #pragma unroll
  for (int q = 0; q < 8; ++q) {
    sdp += (double)vv[q] * (double)vv[q];
    unsigned u  = __float_as_uint(vv[q]);
    unsigned hb = (u + 0x7FFFu + ((u >> 16) & 1u)) >> 16;
    float hf    = __uint_as_float(hb << 16);
    float lf    = vv[q] - hf;
    unsigned ul = __float_as_uint(lf);
    unsigned lb = (ul + 0x7FFFu + ((ul >> 16) & 1u)) >> 16;
    h[q] = (short)hb; lo[q] = (short)lb;
  }
  *reinterpret_cast<bf16x8*>(xhi + (size_t)f * 8) = h;
  *reinterpret_cast<bf16x8*>(xlo + (size_t)f * 8) = lo;

  sd[rloc][(tid >> 4)] = sdp;
  __syncthreads();
  if (tid < 16) {
    double s = 0.0;
    #pragma unroll
    for (int q = 0; q < 16; ++q) s += sd[tid][q];
    selfdot[(rg << 4) + tid] = s;
  }
}

// ---- kernel 2: TRIANGULAR MFMA GEMM + mirrored-append epilogue ----
// 1088 jobs: 136 supertile pairs (P<=Q over 16x16 grid of 256x256 tiles) x 8
// sub-jobs (32 rows of P x 256 cols of Q). Off-diagonal cells append to BOTH
// row i (group Q, NCAP slots) and row j (group P, sub-range (rg&7)*MCAP).
// Counts exported for overflow detection -> exact fallback. base DROPPED.
__global__ __launch_bounds__(256) void nca_gemm(
    const short* __restrict__ xhi, const short* __restrict__ xlo,
    const int* __restrict__ tgt, uint2* __restrict__ winbuf,
    unsigned char* __restrict__ wcbufN, unsigned char* __restrict__ wcbufM,
    float* __restrict__ diagneg) {
  __shared__ int wcl[32];                // normal counters (32 rows)
  __shared__ int wcl2[256];              // mirrored counters (256 col-rows)

  const int tid = threadIdx.x;
  const int w   = tid >> 6;
  const int l   = tid & 63;
  // XCD-chunked swizzle over 1088 jobs (136 per XCD, contiguous pair range)
  const int bid = blockIdx.x;
  const int swz = (bid & 7) * 136 + (bid >> 3);
  int tp = swz >> 3;
  const int s8 = swz & 7;
  int P = 0;
  while (tp >= 16 - P) { tp -= 16 - P; ++P; }
  const int Q  = P + tp;
  const int rg = (P << 3) + s8;
  const int cg = Q;
  const bool MIR = (P != Q);
  const int R   = rg << 5;                 // 32 rows
  const int C   = (cg << 8) + (w << 6);    // 64 cols per wave
  const int rga = rg << 1;
  const int rgb = (cg << 4) + (w << 2);

  if (tid < 32) wcl[tid] = 0;
  wcl2[tid] = 0;
  __syncthreads();

  f32x4 acc[2][4];
  #pragma unroll
  for (int rt = 0; rt < 2; ++rt)
    #pragma unroll
    for (int t = 0; t < 4; ++t) acc[rt][t] = (f32x4){0.f, 0.f, 0.f, 0.f};

  #pragma unroll
  for (int kb = 0; kb < 4; ++kb) {
    bf16x8 ah[2], al[2], bh[4], bl[4];
    #pragma unroll
    for (int rt = 0; rt < 2; ++rt) {
      const size_t off = ((size_t)((rga + rt) * 4 + kb) * 64 + l) * 8;
      ah[rt] = *reinterpret_cast<const bf16x8*>(xhi + off);
      al[rt] = *reinterpret_cast<const bf16x8*>(xlo + off);
    }
    #pragma unroll
    for (int t = 0; t < 4; ++t) {
      const size_t off = ((size_t)((rgb + t) * 4 + kb) * 64 + l) * 8;
      bh[t] = *reinterpret_cast<const bf16x8*>(xhi + off);
      bl[t] = *reinterpret_cast<const bf16x8*>(xlo + off);
    }
    #pragma unroll
    for (int rt = 0; rt < 2; ++rt)
      #pragma unroll
      for (int t = 0; t < 4; ++t) {
        acc[rt][t] = __builtin_amdgcn_mfma_f32_16x16x32_bf16(ah[rt], bh[t], acc[rt][t], 0, 0, 0);
        acc[rt][t] = __builtin_amdgcn_mfma_f32_16x16x32_bf16(ah[rt], bl[t], acc[rt][t], 0, 0, 0);
        acc[rt][t] = __builtin_amdgcn_mfma_f32_16x16x32_bf16(al[rt], bh[t], acc[rt][t], 0, 0, 0);
      }
  }

  // C/D layout (m89-verified): col = lane&15, row = (lane>>4)*4 + reg
  const int rbase = (l >> 4) << 2;
  const int cc    = l & 15;
  const unsigned P2k = f2k(P2F);
  const int tN1 = (cg == 15) ? tgt[NN - 1] : 0;

  int tr[2][4], tc[4];
  #pragma unroll
  for (int rt = 0; rt < 2; ++rt)
    #pragma unroll
    for (int r = 0; r < 4; ++r) tr[rt][r] = tgt[R + (rt << 4) + rbase + r];
  #pragma unroll
  for (int t = 0; t < 4; ++t) tc[t] = tgt[C + (t << 4) + cc];

  #pragma unroll
  for (int rt = 0; rt < 2; ++rt) {
    #pragma unroll
    for (int r = 0; r < 4; ++r) {
      const int row_l = (rt << 4) + rbase + r;
      const int grow  = R + row_l;
      #pragma unroll
      for (int t = 0; t < 4; ++t) {
        const float s = acc[rt][t][r];
        const int j = C + (t << 4) + cc;
        const bool same = (tc[t] == tr[rt][r]);
        const unsigned key = f2k(s);
        const bool app = (j != grow) && (same || (key < P2k));
        if (app) {
          int slot = atomicAdd(&wcl[row_l], 1);
          if (slot < NCAP)
            winbuf[(size_t)grow * RSLOT + cg * GSTR + slot] =
                make_uint2(key, same ? 1u : 0u);
          if (MIR) {
            const int idx = j - (cg << 8);
            int m = atomicAdd(&wcl2[idx], 1);
            if (m < MCAP)
              winbuf[(size_t)j * RSLOT + P * GSTR + s8 * MCAP + m] =
                  make_uint2(key, same ? 1u : 0u);
          }
        }
      }
    }
  }

  // last-row (NN-1) negative-pair sim sums (deterministic per-job slots)
  if (cg == 15 && rg == 127) {           // normal: cols 3840..4095 of row NN-1
    float negs = 0.f;
    #pragma unroll
    for (int t = 0; t < 4; ++t) negs += (tc[t] != tN1) ? acc[1][t][3] : 0.f;
    negs = ((l >> 4) == 3) ? negs : 0.f;
    #pragma unroll
    for (int m = 1; m < 16; m <<= 1) negs += __shfl_xor(negs, m, 64);
    if (l == 48) diagneg[128 + w] = negs;
  }
  if (cg == 15 && MIR && w == 3) {       // mirrored: cols R..R+31 of row NN-1
    float nm = 0.f;
    if (cc == 15) {
      #pragma unroll
      for (int rt = 0; rt < 2; ++rt)
        #pragma unroll
        for (int r = 0; r < 4; ++r)
          nm += (tr[rt][r] != tN1) ? acc[rt][3][r] : 0.f;
    }
    nm += __shfl_xor(nm, 16, 64);
    nm += __shfl_xor(nm, 32, 64);
    if (l == 63) diagneg[rg] = nm;
  }

  __syncthreads();
  if (tid < 32) {
    int c = wcl[tid];
    wcbufN[(size_t)(R + tid) * 16 + cg] = (unsigned char)(c > 255 ? 255 : c);
  }
  if (MIR) {
    int c = wcl2[tid];
    wcbufM[(size_t)((cg << 8) + tid) * 128 + (P << 3) + s8] =
        (unsigned char)(c > 255 ? 255 : c);
  }
}

// ---- kernel 3: per-row combine. 1 wave = 1 row; gathers 768 slots. ----
__global__ __launch_bounds__(256) void nca_combine(
    const double* __restrict__ selfdot, const int* __restrict__ tgt,
    const uint2* __restrict__ winbuf, const unsigned char* __restrict__ wcbufN,
    const unsigned char* __restrict__ wcbufM, const float* __restrict__ diagneg,
    int* __restrict__ flag, float* __restrict__ row_loss,
    float* __restrict__ out) {
  const int tid = threadIdx.x, w = tid >> 6, lane = tid & 63;
  const int i = blockIdx.x * 4 + w;
  const int G = i >> 8;                  // row's supertile

  const double selfd = selfdot[i];
  const bool self_pos = (selfd < 1.0);

  // lane g (g<16) holds group-g counts: normal byte + 8 mirrored sub bytes
  const int wcN_l = (lane < 16) ? (int)wcbufN[(size_t)i * 16 + lane] : 0;
  unsigned long long wcM_l = 0;
  if (lane < 16)
    wcM_l = reinterpret_cast<const unsigned long long*>(
        wcbufM + (size_t)i * 128)[lane];

  bool ov = (lane < 16) && (lane >= G) && (wcN_l > NCAP);
  if (lane < 16 && lane < G) {
    #pragma unroll
    for (int b = 0; b < 8; ++b)
      ov |= (((wcM_l >> (b * 8)) & 255ull) > (unsigned long long)MCAP);
  }
  const bool ovf = (__ballot(ov) != 0ull);

  // gather 12 slots/lane: sigma = q*64+lane; group = sigma/48, slot = sigma%48
  unsigned k[12];
  int smask = 0;
  #pragma unroll
  for (int q = 0; q < 12; ++q) k[q] = 0xFFFFFFFFu;
  #pragma unroll
  for (int q = 0; q < 12; ++q) {
    const int sigma = (q << 6) + lane;
    const int grp  = sigma / GSTR;
    const int slot = sigma - grp * GSTR;
    const int cN = __shfl(wcN_l, grp, 64);
    const unsigned long long mM = __shfl(wcM_l, grp, 64);
    bool valid;
    if (grp >= G) {
      valid = slot < cN;                 // slot < 48 always; cap==48
    } else {
      const int sub = slot / MCAP;
      const int within = slot - sub * MCAP;
      const int cM = (int)((mM >> (sub * 8)) & 255ull);
      valid = within < (cM < MCAP ? cM : MCAP);
    }
    if (valid) {
      uint2 e = winbuf[(size_t)i * RSLOT + sigma];
      k[q] = e.x;
      smask |= (int)e.y << q;
    }
  }

  const unsigned P2k = f2k(P2F);
  int c2 = 0;
  #pragma unroll
  for (int q = 0; q < 12; ++q) c2 += (int)__popcll(__ballot(k[q] < P2k));
  const bool fast = (c2 > KSEL) && (!ovf);
  if (!fast) {
    if (lane == 0) { int p = atomicAdd(&flag[0], 1); flag[1 + p] = i; }
    return;
  }

  // exact rank-KSEL key: max u with count(keys < u) <= KSEL
  unsigned thrkey = 0;
  for (int b = 31; b >= 0; --b) {
    unsigned mid = thrkey | (1u << b);
    int c = 0;
    #pragma unroll
    for (int q = 0; q < 12; ++q) c += (int)__popcll(__ballot(k[q] < mid));
    if (c <= KSEL) thrkey = mid;
  }

  float wp = 0.f, wn = 0.f, minp = __builtin_inff();
  int hp = 0;
  #pragma unroll
  for (int q = 0; q < 12; ++q) {
    const float s = k2f(k[q]);           // NaN for empty slots
    const bool sq = (smask >> q) & 1;
    if (k[q] < thrkey) {
      float e = expf(-ALPHA_C * s);
      if (sq) { wp += e; hp = 1; } else wn += e;
    }
    if (sq && s < 1.0f) minp = fminf(minp, s);
  }
  wp = wsum_f(wp); wn = wsum_f(wn); hp = wsum_i(hp); minp = wmin_f(minp);

  const float minp2 = self_pos ? fminf(minp, (float)selfd) : minp;
  const float pl = hp ? wp : expf(-ALPHA_C * minp2);
  const float nl = wn;
  if (lane == 0) row_loss[i] = -logf(pl / (pl + nl));

  if (i == NN - 1) {                     // diagnostics from the last row
    float ps = 0.f; int pc = 0;
    #pragma unroll
    for (int q = 0; q < 12; ++q) {
      const float s = k2f(k[q]);
      if (((smask >> q) & 1) && s < 1.0f) { ps += s; pc++; }
    }
    ps = wsum_f(ps); pc = wsum_i(pc);
    float ns = 0.f;
    for (int idx = lane; idx < 136; idx += 64) ns += diagneg[idx];
    ns = wsum_f(ns);
    const int ti = tgt[NN - 1];
    int nc = 0;
    #pragma unroll
    for (int kk = 0; kk < 16; ++kk) {
      int4 t4 = *reinterpret_cast<const int4*>(tgt + (kk << 8) + (lane << 2));
      nc += (t4.x != ti) + (t4.y != ti) + (t4.z != ti) + (t4.w != ti);
    }
    nc = wsum_i(nc);
    if (lane == 0) {
      out[2] = (ps + (self_pos ? (float)selfd : 0.f)) /
               (float)(pc + (self_pos ? 1 : 0));
      out[3] = ns / (float)nc;
    }
  }
}

// ---- kernel 4: exact fallback, stride loop over flagged rows ----
__global__ __launch_bounds__(256) void nca_fallback(
    const float* __restrict__ x, const int* __restrict__ tgt,
    const int* __restrict__ flag, float* __restrict__ row_loss,
    float* __restrict__ out) {
  __shared__ float xi[DD];
  __shared__ double redD[4];
  __shared__ int redI[2][4];
  __shared__ double redP[4], redN[4];
  __shared__ float redM[4];
  __shared__ int redH[4], redC[4], redC2[4];
  __shared__ unsigned cbuf[64];
  __shared__ int ccount;

  const int nf = flag[0];
  const int tid = threadIdx.x, w = tid >> 6, lane = tid & 63;
  for (int fi = blockIdx.x; fi < nf; fi += (int)gridDim.x) {
    __syncthreads();
    const int i = flag[1 + fi];
    const int ti = tgt[i];
    if (tid < DD) xi[tid] = x[(size_t)i * DD + tid];
    __syncthreads();

    float sims[16];
    const float4* xiv = reinterpret_cast<const float4*>(xi);
    for (int c = 0; c < 16; ++c) {
      const int j = (c << 8) + tid;
      const float4* xj = reinterpret_cast<const float4*>(x + (size_t)j * DD);
      float a0 = 0, a1 = 0, a2 = 0, a3 = 0;
      #pragma unroll
      for (int d = 0; d < 32; ++d) {
        float4 u = xiv[d]; float4 v = xj[d];
        a0 = fmaf(u.x, v.x, a0); a1 = fmaf(u.y, v.y, a1);
        a2 = fmaf(u.z, v.z, a2); a3 = fmaf(u.w, v.w, a3);
      }
      sims[c] = (a0 + a1) + (a2 + a3);
    }

    double sx0 = (double)xi[lane], sx1 = (double)xi[lane + 64];
    const double selfd = wsum_d(sx0 * sx0 + sx1 * sx1);
    const bool self_pos = (selfd < 1.0);

    unsigned kv[16];
    double bs = 0.0;
    #pragma unroll
    for (int c = 0; c < 16; ++c) { bs += (double)sims[c]; kv[c] = f2k(sims[c]); }
    if (!self_pos && ((i & 255) == tid)) kv[i >> 8] = 0xFFFFFFFFu;

    bs = wsum_d(bs);
    if (lane == 0) redD[w] = bs;
    __syncthreads();
    const float basef = (float)((redD[0] + redD[1] + redD[2] + redD[3]) * (1.0 / NN));

    unsigned lo = 0;
    int nLo = 0, nHi = NN, b = 31, par = 0;
    while (b >= 0 && (nHi - nLo) > 64) {
      unsigned mid = lo | (1u << b);
      int c = 0;
      #pragma unroll
      for (int t = 0; t < 16; ++t) c += (kv[t] < mid) ? 1 : 0;
      c = wsum_i(c);
      if (lane == 0) redI[par][w] = c;
      __syncthreads();
      c = redI[par][0] + redI[par][1] + redI[par][2] + redI[par][3];
      par ^= 1;
      if (c <= KSEL) { lo = mid; nLo = c; }
      else nHi = c;
      --b;
    }
    unsigned keysel;
    if ((nHi - nLo) <= 64) {
      const int shift = b + 1;
      const unsigned pfx = lo >> shift;
      if (tid == 0) ccount = 0;
      __syncthreads();
      #pragma unroll
      for (int t = 0; t < 16; ++t)
        if ((kv[t] >> shift) == pfx) { int p = atomicAdd(&ccount, 1); cbuf[p] = kv[t]; }
      __syncthreads();
      const int total = ccount;
      unsigned v = cbuf[lane];
      unsigned long long amask = (total >= 64) ? ~0ull : ((1ull << total) - 1ull);
      int ww = KSEL - nLo;
      for (int bb = b; bb >= 0; --bb) {
        unsigned long long z = __ballot(((amask >> lane) & 1ull) &&
                                        (((v >> bb) & 1u) == 0u));
        int zc = __popcll(z);
        if (ww < zc) amask = z;
        else { ww -= zc; amask &= ~z; }
      }
      int first = __ffsll((unsigned long long)amask) - 1;
      keysel = __shfl(v, first, 64);
    } else {
      keysel = lo;
    }
    const float thr = k2f(keysel);

    double psum = 0.0, nsum = 0.0;
    float minp = __builtin_inff();
    int hasp = 0;
    double pss = 0.0, nss = 0.0;
    int pct = 0, nct = 0;
    #pragma unroll
    for (int c = 0; c < 16; ++c) {
      const int j = (c << 8) + tid;
      const float s = k2f(kv[c]);
      const bool same = (tgt[j] == ti);
      const bool vpos = same && ((j == i) ? self_pos : (s < 1.0f));
      if (vpos) { minp = fminf(minp, s); pss += (double)s; pct++; }
      if (!same) { nss += (double)s; nct++; }
      if (s < thr) {
        float wgt = expf(ALPHA_C * (basef - s));
        if (vpos) { psum += (double)wgt; hasp = 1; }
        else if (!same) nsum += (double)wgt;
      }
    }
    psum = wsum_d(psum); nsum = wsum_d(nsum);
    minp = wmin_f(minp); hasp = wsum_i(hasp);
    if (lane == 0) { redP[w] = psum; redN[w] = nsum; redM[w] = minp; redH[w] = hasp; }
    __syncthreads();
    const double tpsum = redP[0] + redP[1] + redP[2] + redP[3];
    const double tnsum = redN[0] + redN[1] + redN[2] + redN[3];
    const float  tminp = fminf(fminf(redM[0], redM[1]), fminf(redM[2], redM[3]));
    const int    thasp = redH[0] + redH[1] + redH[2] + redH[3];

    if (i == NN - 1) {
      __syncthreads();
      pss = wsum_d(pss); nss = wsum_d(nss);
      pct = wsum_i(pct); nct = wsum_i(nct);
      if (lane == 0) { redP[w] = pss; redN[w] = nss; redC[w] = pct; redC2[w] = nct; }
      __syncthreads();
      if (tid == 0) {
        out[2] = (float)((redP[0] + redP[1] + redP[2] + redP[3]) /
                         (double)(redC[0] + redC[1] + redC[2] + redC[3]));
        out[3] = (float)((redN[0] + redN[1] + redN[2] + redN[3]) /
                         (double)(redC2[0] + redC2[1] + redC2[2] + redC2[3]));
      }
    }
    if (tid == 0) {
      float pl = (thasp > 0) ? (float)tpsum : expf(ALPHA_C * (basef - tminp));
      row_loss[i] = -logf(pl / (pl + (float)tnsum));
    }
  }
}

// ---- kernel 5: deterministic mean of per-row losses ----
__global__ void nca_final(const float* __restrict__ row_loss, float* __restrict__ out) {
  __shared__ double redd[4];
  int tid = threadIdx.x;
  double s = 0.0;
  for (int i = tid; i < NN; i += 256) s += (double)row_loss[i];
  #pragma unroll
  for (int m = 32; m; m >>= 1) s += __shfl_xor(s, m, 64);
  if ((tid & 63) == 0) redd[tid >> 6] = s;
  __syncthreads();
  if (tid == 0) {
    double tot = redd[0] + redd[1] + redd[2] + redd[3];
    out[0] = (float)(tot * (1.0 / NN));
    out[1] = 0.0f;
  }
}

extern "C" void kernel_launch(void* const* d_in, const int* in_sizes, int n_in,
                              void* d_out, int out_size, void* d_ws, size_t ws_size,
                              hipStream_t stream) {
  const float* x  = (const float*)d_in[0];
  const int* tgt  = (const int*)d_in[1];
  float* out      = (float*)d_out;

  // ws: xhi 1MB | xlo 1MB | row_loss 16KB | selfdot 32KB | winbuf 24MB |
  //     wcbufN 64KB | wcbufM 512KB | diagneg 544B | flag
  short* xhi      = (short*)d_ws;
  short* xlo      = xhi + (size_t)NN * DD;
  float* row_loss = (float*)(xlo + (size_t)NN * DD);
  double* selfdot = (double*)(row_loss + NN);
  uint2* winbuf   = (uint2*)(selfdot + NN);
  unsigned char* wcbufN = (unsigned char*)(winbuf + (size_t)NN * RSLOT);
  unsigned char* wcbufM = wcbufN + (size_t)NN * 16;
  float* diagneg  = (float*)(wcbufM + (size_t)NN * 128);
  int* flag       = (int*)(diagneg + 136);

  nca_prep<<<NN / 16, 256, 0, stream>>>(x, xhi, xlo, selfdot, diagneg, flag);
  nca_gemm<<<1088, 256, 0, stream>>>(xhi, xlo, tgt, winbuf, wcbufN, wcbufM, diagneg);
  nca_combine<<<NN / 4, 256, 0, stream>>>(selfdot, tgt, winbuf, wcbufN, wcbufM,
                                          diagneg, flag, row_loss, out);
  nca_fallback<<<256, 256, 0, stream>>>(x, tgt, flag, row_loss, out);
  nca_final<<<1, 256, 0, stream>>>(row_loss, out);
}

// Round 22
// 47.147 us; speedup vs baseline: 1.2237x; 1.2237x over previous
//
#include <hip/hip_runtime.h>
#include <hip/hip_cooperative_groups.h>
#include <math.h>

namespace cg = cooperative_groups;

#define NN 4096
#define DD 128
#define ALPHA_C 16.0f
#define KSEL 32         // threshold = (K+1)-th smallest, 0-based index K
#define P2F -0.19f      // pivot: rank-32 of N(0,1/128) sims is ~-0.213, below P2
#define SLOTS 16        // slots per (row, colblock); appends ~Poisson(4.6)

typedef __attribute__((ext_vector_type(8))) short bf16x8;
typedef __attribute__((ext_vector_type(4))) float f32x4;

// ---- float <-> order-preserving u32 key ----
__device__ __forceinline__ unsigned f2k(float f) {
  unsigned b = __float_as_uint(f);
  return (b & 0x80000000u) ? ~b : (b | 0x80000000u);
}
__device__ __forceinline__ float k2f(unsigned k) {
  unsigned b = (k & 0x80000000u) ? (k & 0x7FFFFFFFu) : ~k;
  return __uint_as_float(b);
}

// ---- wave (64-lane) butterfly reductions ----
__device__ __forceinline__ double wsum_d(double v) {
  #pragma unroll
  for (int m = 32; m; m >>= 1) v += __shfl_xor(v, m, 64);
  return v;
}
__device__ __forceinline__ int wsum_i(int v) {
  #pragma unroll
  for (int m = 32; m; m >>= 1) v += __shfl_xor(v, m, 64);
  return v;
}
__device__ __forceinline__ float wsum_f(float v) {
  #pragma unroll
  for (int m = 32; m; m >>= 1) v += __shfl_xor(v, m, 64);
  return v;
}
__device__ __forceinline__ float wmin_f(float v) {
  #pragma unroll
  for (int m = 32; m; m >>= 1) v = fminf(v, __shfl_xor(v, m, 64));
  return v;
}

// ======== phase bodies (shared by fused cooperative kernel and standalone) ====

// prep: split x -> bf16 hi/lo fragment-major; f64 self-dots. bid in [0,256).
__device__ __forceinline__ void prep_body(
    int bid, int tid, const float* __restrict__ x, short* __restrict__ xhi,
    short* __restrict__ xlo, double* __restrict__ selfdot, int* __restrict__ flag,
    double (*sd)[16]) {
  const int f  = bid * 256 + tid;          // 0 .. N*D/8-1
  if (f == 0) flag[0] = 0;
  const int l  = f & 63;
  const int kb = (f >> 6) & 3;
  const int rg = f >> 8;                   // == bid
  const int rloc = l & 15;
  const int row = (rg << 4) + rloc;
  const int k0  = (kb << 5) + ((l >> 4) << 3);
  const float* src = x + (size_t)row * DD + k0;
  float4 v0 = *reinterpret_cast<const float4*>(src);
  float4 v1 = *reinterpret_cast<const float4*>(src + 4);
  float vv[8] = {v0.x, v0.y, v0.z, v0.w, v1.x, v1.y, v1.z, v1.w};
  bf16x8 h, lo;
  double sdp = 0.0;
  #pragma unroll
  for (int q = 0; q < 8; ++q) {
    sdp += (double)vv[q] * (double)vv[q];
    unsigned u  = __float_as_uint(vv[q]);
    unsigned hb = (u + 0x7FFFu + ((u >> 16) & 1u)) >> 16;
    float hf    = __uint_as_float(hb << 16);
    float lf    = vv[q] - hf;
    unsigned ul = __float_as_uint(lf);
    unsigned lb = (ul + 0x7FFFu + ((ul >> 16) & 1u)) >> 16;
    h[q] = (short)hb; lo[q] = (short)lb;
  }
  *reinterpret_cast<bf16x8*>(xhi + (size_t)f * 8) = h;
  *reinterpret_cast<bf16x8*>(xlo + (size_t)f * 8) = lo;

  sd[rloc][(tid >> 4)] = sdp;
  __syncthreads();
  if (tid < 16) {
    double s = 0.0;
    #pragma unroll
    for (int q = 0; q < 16; ++q) s += sd[tid][q];
    selfdot[(rg << 4) + tid] = s;
  }
  __syncthreads();
}

// gemm: 32x256 tile (round-18 proven), vb in [0,2048). Minimal epilogue:
// candidate list (key<P2 or same-class) to fixed slots + counts + diag.
__device__ __forceinline__ void gemm_body(
    int vb, int tid, const short* __restrict__ xhi, const short* __restrict__ xlo,
    const int* __restrict__ tgt, uint2* __restrict__ winbuf,
    unsigned char* __restrict__ wcbuf, float* __restrict__ diagneg, int* wcl) {
  const int w   = tid >> 6;
  const int l   = tid & 63;
  // XCD-chunked bijective swizzle over 2048 jobs
  const int swz = ((vb & 7) << 8) + (vb >> 3);
  const int rg  = swz >> 4;                // 0..127
  const int cg  = swz & 15;
  const int R   = rg << 5;                 // 32 rows
  const int C   = (cg << 8) + (w << 6);    // 64 cols per wave
  const int rga = rg << 1;
  const int rgb = (cg << 4) + (w << 2);

  if (tid < 32) wcl[tid] = 0;
  __syncthreads();

  f32x4 acc[2][4];
  #pragma unroll
  for (int rt = 0; rt < 2; ++rt)
    #pragma unroll
    for (int t = 0; t < 4; ++t) acc[rt][t] = (f32x4){0.f, 0.f, 0.f, 0.f};

  #pragma unroll
  for (int kb = 0; kb < 4; ++kb) {
    bf16x8 ah[2], al[2], bh[4], bl[4];
    #pragma unroll
    for (int rt = 0; rt < 2; ++rt) {
      const size_t off = ((size_t)((rga + rt) * 4 + kb) * 64 + l) * 8;
      ah[rt] = *reinterpret_cast<const bf16x8*>(xhi + off);
      al[rt] = *reinterpret_cast<const bf16x8*>(xlo + off);
    }
    #pragma unroll
    for (int t = 0; t < 4; ++t) {
      const size_t off = ((size_t)((rgb + t) * 4 + kb) * 64 + l) * 8;
      bh[t] = *reinterpret_cast<const bf16x8*>(xhi + off);
      bl[t] = *reinterpret_cast<const bf16x8*>(xlo + off);
    }
    #pragma unroll
    for (int rt = 0; rt < 2; ++rt)
      #pragma unroll
      for (int t = 0; t < 4; ++t) {
        acc[rt][t] = __builtin_amdgcn_mfma_f32_16x16x32_bf16(ah[rt], bh[t], acc[rt][t], 0, 0, 0);
        acc[rt][t] = __builtin_amdgcn_mfma_f32_16x16x32_bf16(ah[rt], bl[t], acc[rt][t], 0, 0, 0);
        acc[rt][t] = __builtin_amdgcn_mfma_f32_16x16x32_bf16(al[rt], bh[t], acc[rt][t], 0, 0, 0);
      }
  }

  // C/D layout (m89-verified): col = lane&15, row = (lane>>4)*4 + reg
  const int rbase = (l >> 4) << 2;
  const int cc    = l & 15;
  const unsigned P2k = f2k(P2F);
  const bool diagblk = (R + 32 == NN);

  int tr[2][4], tc[4];
  #pragma unroll
  for (int rt = 0; rt < 2; ++rt)
    #pragma unroll
    for (int r = 0; r < 4; ++r) tr[rt][r] = tgt[R + (rt << 4) + rbase + r];
  #pragma unroll
  for (int t = 0; t < 4; ++t) tc[t] = tgt[C + (t << 4) + cc];

  #pragma unroll
  for (int rt = 0; rt < 2; ++rt) {
    #pragma unroll
    for (int r = 0; r < 4; ++r) {
      const int row_l = (rt << 4) + rbase + r;
      const int grow  = R + row_l;
      #pragma unroll
      for (int t = 0; t < 4; ++t) {
        const float s = acc[rt][t][r];
        const int j = C + (t << 4) + cc;
        const bool same = (tc[t] == tr[rt][r]);
        const unsigned key = f2k(s);
        const bool app = (j != grow) && (same || (key < P2k));
        if (app) {
          int slot = atomicAdd(&wcl[row_l], 1);
          if (slot < SLOTS)
            winbuf[(size_t)grow * 256 + (cg << 4) + slot] =
                make_uint2(key, same ? 1u : 0u);
        }
      }
    }
  }

  if (diagblk) {   // last-row (NN-1) negative-pair sim sum
    const int tN1 = tgt[NN - 1];
    float negs = 0.f;
    #pragma unroll
    for (int t = 0; t < 4; ++t)
      negs += (tc[t] != tN1) ? acc[1][t][3] : 0.f;
    negs = ((l >> 4) == 3) ? negs : 0.f;   // only group 3 holds row NN-1
    #pragma unroll
    for (int m = 1; m < 16; m <<= 1) negs += __shfl_xor(negs, m, 64);
    if (l == 48) diagneg[(cg << 2) + w] = negs;
  }

  __syncthreads();
  if (tid < 32) {
    int c = wcl[tid];
    wcbuf[(size_t)(R + tid) * 16 + cg] = (unsigned char)(c > 255 ? 255 : c);
  }
  __syncthreads();
}

// combine: 1 wave = 1 row; complete info from candidate list. bid in [0,1024).
__device__ __forceinline__ void combine_body(
    int bid, int tid, const double* __restrict__ selfdot,
    const int* __restrict__ tgt, const uint2* __restrict__ winbuf,
    const unsigned char* __restrict__ wcbuf, const float* __restrict__ diagneg,
    int* __restrict__ flag, float* __restrict__ row_loss,
    float* __restrict__ out) {
  const int w = tid >> 6, lane = tid & 63;
  const int i = bid * 4 + w;

  const double selfd = selfdot[i];
  const bool self_pos = (selfd < 1.0);

  const int wcq_l = (lane < 16) ? (int)wcbuf[(size_t)i * 16 + lane] : 0;
  const bool ovf = (__ballot(wcq_l > SLOTS) != 0ull);

  unsigned k[4]  = {0xFFFFFFFFu, 0xFFFFFFFFu, 0xFFFFFFFFu, 0xFFFFFFFFu};
  unsigned sm[4] = {0u, 0u, 0u, 0u};
  #pragma unroll
  for (int q = 0; q < 4; ++q) {
    const int sigma = (q << 6) + lane;
    const int wcq = __shfl(wcq_l, sigma >> 4, 64);
    if ((sigma & 15) < (wcq < SLOTS ? wcq : SLOTS)) {
      uint2 e = winbuf[(size_t)i * 256 + sigma];
      k[q] = e.x; sm[q] = e.y;
    }
  }

  const unsigned P2k = f2k(P2F);
  int c2 = 0;
  #pragma unroll
  for (int q = 0; q < 4; ++q) c2 += (int)__popcll(__ballot(k[q] < P2k));
  const bool fast = (c2 > KSEL) && (!ovf);
  if (!fast) {
    if (lane == 0) { int p = atomicAdd(&flag[0], 1); flag[1 + p] = i; }
    return;
  }

  unsigned thrkey = 0;
  for (int b = 31; b >= 0; --b) {
    unsigned mid = thrkey | (1u << b);
    int c = 0;
    #pragma unroll
    for (int q = 0; q < 4; ++q) c += (int)__popcll(__ballot(k[q] < mid));
    if (c <= KSEL) thrkey = mid;
  }

  float wp = 0.f, wn = 0.f, minp = __builtin_inff();
  int hp = 0;
  #pragma unroll
  for (int q = 0; q < 4; ++q) {
    const float s = k2f(k[q]);           // NaN for empty slots
    if (k[q] < thrkey) {
      float e = expf(-ALPHA_C * s);
      if (sm[q]) { wp += e; hp = 1; } else wn += e;
    }
    if (sm[q] && s < 1.0f) minp = fminf(minp, s);
  }
  wp = wsum_f(wp); wn = wsum_f(wn); hp = wsum_i(hp); minp = wmin_f(minp);

  const float minp2 = self_pos ? fminf(minp, (float)selfd) : minp;
  const float pl = hp ? wp : expf(-ALPHA_C * minp2);
  const float nl = wn;
  if (lane == 0) row_loss[i] = -logf(pl / (pl + nl));

  if (i == NN - 1) {
    float ps = 0.f; int pc = 0;
    #pragma unroll
    for (int q = 0; q < 4; ++q) {
      const float s = k2f(k[q]);
      if (sm[q] && s < 1.0f) { ps += s; pc++; }
    }
    ps = wsum_f(ps); pc = wsum_i(pc);
    float ns = wsum_f(diagneg[lane]);
    const int ti = tgt[NN - 1];
    int nc = 0;
    #pragma unroll
    for (int kk = 0; kk < 16; ++kk) {
      int4 t4 = *reinterpret_cast<const int4*>(tgt + (kk << 8) + (lane << 2));
      nc += (t4.x != ti) + (t4.y != ti) + (t4.z != ti) + (t4.w != ti);
    }
    nc = wsum_i(nc);
    if (lane == 0) {
      out[2] = (ps + (self_pos ? (float)selfd : 0.f)) /
               (float)(pc + (self_pos ? 1 : 0));
      out[3] = ns / (float)nc;
    }
  }
}

// ======== fused cooperative kernel: prep -> gemm -> combine ========
__global__ __launch_bounds__(256) void nca_fused(
    const float* __restrict__ x, const int* __restrict__ tgt,
    short* __restrict__ xhi, short* __restrict__ xlo,
    double* __restrict__ selfdot, uint2* __restrict__ winbuf,
    unsigned char* __restrict__ wcbuf, float* __restrict__ diagneg,
    int* __restrict__ flag, float* __restrict__ row_loss,
    float* __restrict__ out) {
  __shared__ double sd[16][16];
  __shared__ int wcl[32];
  cg::grid_group grid = cg::this_grid();
  const int tid = threadIdx.x;
  const int bid = blockIdx.x;          // 1024 blocks

  if (bid < 256) prep_body(bid, tid, x, xhi, xlo, selfdot, flag, sd);
  __threadfence();
  grid.sync();

  #pragma unroll
  for (int j = 0; j < 2; ++j)
    gemm_body(bid * 2 + j, tid, xhi, xlo, tgt, winbuf, wcbuf, diagneg, wcl);
  __threadfence();
  grid.sync();

  combine_body(bid, tid, selfdot, tgt, winbuf, wcbuf, diagneg, flag, row_loss, out);
}

// ======== standalone wrappers (fallback path if coop not resident) ========
__global__ __launch_bounds__(256) void nca_prep_k(
    const float* __restrict__ x, short* __restrict__ xhi, short* __restrict__ xlo,
    double* __restrict__ selfdot, int* __restrict__ flag) {
  __shared__ double sd[16][16];
  prep_body(blockIdx.x, threadIdx.x, x, xhi, xlo, selfdot, flag, sd);
}
__global__ __launch_bounds__(256) void nca_gemm_k(
    const short* __restrict__ xhi, const short* __restrict__ xlo,
    const int* __restrict__ tgt, uint2* __restrict__ winbuf,
    unsigned char* __restrict__ wcbuf, float* __restrict__ diagneg) {
  __shared__ int wcl[32];
  gemm_body(blockIdx.x, threadIdx.x, xhi, xlo, tgt, winbuf, wcbuf, diagneg, wcl);
}
__global__ __launch_bounds__(256) void nca_combine_k(
    const double* __restrict__ selfdot, const int* __restrict__ tgt,
    const uint2* __restrict__ winbuf, const unsigned char* __restrict__ wcbuf,
    const float* __restrict__ diagneg, int* __restrict__ flag,
    float* __restrict__ row_loss, float* __restrict__ out) {
  combine_body(blockIdx.x, threadIdx.x, selfdot, tgt, winbuf, wcbuf, diagneg,
               flag, row_loss, out);
}

// ---- exact fallback: stride loop over flagged rows (usually none) ----
__global__ __launch_bounds__(256) void nca_fallback(
    const float* __restrict__ x, const int* __restrict__ tgt,
    const int* __restrict__ flag, float* __restrict__ row_loss,
    float* __restrict__ out) {
  __shared__ float xi[DD];
  __shared__ double redD[4];
  __shared__ int redI[2][4];
  __shared__ double redP[4], redN[4];
  __shared__ float redM[4];
  __shared__ int redH[4], redC[4], redC2[4];
  __shared__ unsigned cbuf[64];
  __shared__ int ccount;

  const int nf = flag[0];
  const int tid = threadIdx.x, w = tid >> 6, lane = tid & 63;
  for (int fi = blockIdx.x; fi < nf; fi += (int)gridDim.x) {
    __syncthreads();                     // protect shared reuse across iters
    const int i = flag[1 + fi];
    const int ti = tgt[i];
    if (tid < DD) xi[tid] = x[(size_t)i * DD + tid];
    __syncthreads();

    float sims[16];
    const float4* xiv = reinterpret_cast<const float4*>(xi);
    for (int c = 0; c < 16; ++c) {
      const int j = (c << 8) + tid;
      const float4* xj = reinterpret_cast<const float4*>(x + (size_t)j * DD);
      float a0 = 0, a1 = 0, a2 = 0, a3 = 0;
      #pragma unroll
      for (int d = 0; d < 32; ++d) {
        float4 u = xiv[d]; float4 v = xj[d];
        a0 = fmaf(u.x, v.x, a0); a1 = fmaf(u.y, v.y, a1);
        a2 = fmaf(u.z, v.z, a2); a3 = fmaf(u.w, v.w, a3);
      }
      sims[c] = (a0 + a1) + (a2 + a3);
    }

    double sx0 = (double)xi[lane], sx1 = (double)xi[lane + 64];
    const double selfd = wsum_d(sx0 * sx0 + sx1 * sx1);
    const bool self_pos = (selfd < 1.0);

    unsigned kv[16];
    double bs = 0.0;
    #pragma unroll
    for (int c = 0; c < 16; ++c) { bs += (double)sims[c]; kv[c] = f2k(sims[c]); }
    if (!self_pos && ((i & 255) == tid)) kv[i >> 8] = 0xFFFFFFFFu;

    bs = wsum_d(bs);
    if (lane == 0) redD[w] = bs;
    __syncthreads();
    const float basef = (float)((redD[0] + redD[1] + redD[2] + redD[3]) * (1.0 / NN));

    unsigned lo = 0;
    int nLo = 0, nHi = NN, b = 31, par = 0;
    while (b >= 0 && (nHi - nLo) > 64) {
      unsigned mid = lo | (1u << b);
      int c = 0;
      #pragma unroll
      for (int t = 0; t < 16; ++t) c += (kv[t] < mid) ? 1 : 0;
      c = wsum_i(c);
      if (lane == 0) redI[par][w] = c;
      __syncthreads();
      c = redI[par][0] + redI[par][1] + redI[par][2] + redI[par][3];
      par ^= 1;
      if (c <= KSEL) { lo = mid; nLo = c; }
      else nHi = c;
      --b;
    }
    unsigned keysel;
    if ((nHi - nLo) <= 64) {
      const int shift = b + 1;
      const unsigned pfx = lo >> shift;
      if (tid == 0) ccount = 0;
      __syncthreads();
      #pragma unroll
      for (int t = 0; t < 16; ++t)
        if ((kv[t] >> shift) == pfx) { int p = atomicAdd(&ccount, 1); cbuf[p] = kv[t]; }
      __syncthreads();
      const int total = ccount;
      unsigned v = cbuf[lane];
      unsigned long long amask = (total >= 64) ? ~0ull : ((1ull << total) - 1ull);
      int ww = KSEL - nLo;
      for (int bb = b; bb >= 0; --bb) {
        unsigned long long z = __ballot(((amask >> lane) & 1ull) &&
                                        (((v >> bb) & 1u) == 0u));
        int zc = __popcll(z);
        if (ww < zc) amask = z;
        else { ww -= zc; amask &= ~z; }
      }
      int first = __ffsll((unsigned long long)amask) - 1;
      keysel = __shfl(v, first, 64);
    } else {
      keysel = lo;
    }
    const float thr = k2f(keysel);

    double psum = 0.0, nsum = 0.0;
    float minp = __builtin_inff();
    int hasp = 0;
    double pss = 0.0, nss = 0.0;
    int pct = 0, nct = 0;
    #pragma unroll
    for (int c = 0; c < 16; ++c) {
      const int j = (c << 8) + tid;
      const float s = k2f(kv[c]);
      const bool same = (tgt[j] == ti);
      const bool vpos = same && ((j == i) ? self_pos : (s < 1.0f));
      if (vpos) { minp = fminf(minp, s); pss += (double)s; pct++; }
      if (!same) { nss += (double)s; nct++; }
      if (s < thr) {
        float wgt = expf(ALPHA_C * (basef - s));
        if (vpos) { psum += (double)wgt; hasp = 1; }
        else if (!same) nsum += (double)wgt;
      }
    }
    psum = wsum_d(psum); nsum = wsum_d(nsum);
    minp = wmin_f(minp); hasp = wsum_i(hasp);
    if (lane == 0) { redP[w] = psum; redN[w] = nsum; redM[w] = minp; redH[w] = hasp; }
    __syncthreads();
    const double tpsum = redP[0] + redP[1] + redP[2] + redP[3];
    const double tnsum = redN[0] + redN[1] + redN[2] + redN[3];
    const float  tminp = fminf(fminf(redM[0], redM[1]), fminf(redM[2], redM[3]));
    const int    thasp = redH[0] + redH[1] + redH[2] + redH[3];

    if (i == NN - 1) {
      __syncthreads();
      pss = wsum_d(pss); nss = wsum_d(nss);
      pct = wsum_i(pct); nct = wsum_i(nct);
      if (lane == 0) { redP[w] = pss; redN[w] = nss; redC[w] = pct; redC2[w] = nct; }
      __syncthreads();
      if (tid == 0) {
        out[2] = (float)((redP[0] + redP[1] + redP[2] + redP[3]) /
                         (double)(redC[0] + redC[1] + redC[2] + redC[3]));
        out[3] = (float)((redN[0] + redN[1] + redN[2] + redN[3]) /
                         (double)(redC2[0] + redC2[1] + redC2[2] + redC2[3]));
      }
    }
    if (tid == 0) {
      float pl = (thasp > 0) ? (float)tpsum : expf(ALPHA_C * (basef - tminp));
      row_loss[i] = -logf(pl / (pl + (float)tnsum));
    }
  }
}

// ---- deterministic mean of per-row losses ----
__global__ void nca_final(const float* __restrict__ row_loss, float* __restrict__ out) {
  __shared__ double redd[4];
  int tid = threadIdx.x;
  double s = 0.0;
  for (int i = tid; i < NN; i += 256) s += (double)row_loss[i];
  #pragma unroll
  for (int m = 32; m; m >>= 1) s += __shfl_xor(s, m, 64);
  if ((tid & 63) == 0) redd[tid >> 6] = s;
  __syncthreads();
  if (tid == 0) {
    double tot = redd[0] + redd[1] + redd[2] + redd[3];
    out[0] = (float)(tot * (1.0 / NN));
    out[1] = 0.0f;
  }
}

extern "C" void kernel_launch(void* const* d_in, const int* in_sizes, int n_in,
                              void* d_out, int out_size, void* d_ws, size_t ws_size,
                              hipStream_t stream) {
  const float* x  = (const float*)d_in[0];
  const int* tgt  = (const int*)d_in[1];
  float* out      = (float*)d_out;

  // ws: xhi 1MB | xlo 1MB | row_loss 16KB | selfdot 32KB | winbuf 8MB | wcbuf 64KB | diagneg | flag
  short* xhi      = (short*)d_ws;
  short* xlo      = xhi + (size_t)NN * DD;
  float* row_loss = (float*)(xlo + (size_t)NN * DD);
  double* selfdot = (double*)(row_loss + NN);
  uint2* winbuf   = (uint2*)(selfdot + NN);
  unsigned char* wcbuf = (unsigned char*)(winbuf + (size_t)NN * 256);
  float* diagneg  = (float*)(wcbuf + (size_t)NN * 16);
  int* flag       = (int*)(diagneg + 64);

  // cooperative path needs 1024 blocks co-resident (4 per CU on 256 CUs)
  int maxb = 0;
  hipError_t oe = hipOccupancyMaxActiveBlocksPerMultiprocessor(
      &maxb, (const void*)nca_fused, 256, 0);
  const bool coop = (oe == hipSuccess) && (maxb >= 4);

  if (coop) {
    void* args[] = {(void*)&x, (void*)&tgt, (void*)&xhi, (void*)&xlo,
                    (void*)&selfdot, (void*)&winbuf, (void*)&wcbuf,
                    (void*)&diagneg, (void*)&flag, (void*)&row_loss,
                    (void*)&out};
    hipLaunchCooperativeKernel((const void*)nca_fused, dim3(1024), dim3(256),
                               args, 0, stream);
  } else {
    nca_prep_k<<<NN / 16, 256, 0, stream>>>(x, xhi, xlo, selfdot, flag);
    nca_gemm_k<<<(NN / 32) * (NN / 256), 256, 0, stream>>>(xhi, xlo, tgt,
                                                           winbuf, wcbuf, diagneg);
    nca_combine_k<<<NN / 4, 256, 0, stream>>>(selfdot, tgt, winbuf, wcbuf,
                                              diagneg, flag, row_loss, out);
  }
  nca_fallback<<<256, 256, 0, stream>>>(x, tgt, flag, row_loss, out);
  nca_final<<<1, 256, 0, stream>>>(row_loss, out);
}